// Round 13
// baseline (4014.226 us; speedup 1.0000x reference)
//
#include <hip/hip_runtime.h>
#include <hip/hip_cooperative_groups.h>

// LSTM: B=64, T=256, IN=512, H=1024 (4H=4096), OUT=512. I/O f32.
// Round-23 = r20 (3768us, PROVEN structure) with the ENTIRE datapath
// switched bf16-hi/lo -> single-plane F16:
//   r21/r22 post-mortem: both x-as-counted-asm variants failed
//   identically; r20's counted-region topology is the proven safe
//   envelope -> structure frozen, attack VOLUME instead.
//   r20 budget: ~6us/step unmodeled = LLC BW drain of the h broadcast
//   (sc1 reads have no L2 dedup: 256 blk x ~290KB = ~75MB/step).
//   f16 halves: gate MFMAs (64->32/lane), h loads (64->32), h
//   broadcast (->~38MB/step), A2 (16->8), B stores (2->1), cvt VALU.
//   f16 eps 4.9e-4 is 8x FINER than bf16 for weights/x (the old error
//   driver); h loses the lo plane (2e-5 -> 5e-4) - fine vs 0.0214.
//   f32 MFMA accum, f32 c_reg, f32 gbuf/out unchanged.
// Counted region: r20's exact rotation, counts halved (8-load groups,
// waits 8/8/8/0), staging 64 VGPR (half of r20's proven 128).
// Coherence (r20-proven): h stores sc0sc1 -> vmcnt drain at barrier
// syncthreads -> flag store sc0sc1 -> relaxed poll -> LLC-direct reads.
// NO fences. x/weights stay L2-resident (compiler loads).
// ws: [0,16K) flags; [64K, +384K) h triple buffer (single f16 plane).

#define B_   64
#define T_   256
#define IN_  512
#define H_   1024
#define G4_  4096
#define OUT_ 512
#define KTOT 1536   // IN_ + H_

typedef _Float16 f16x8 __attribute__((ext_vector_type(8)));
typedef float    f4v   __attribute__((ext_vector_type(4)));

__device__ __forceinline__ float sigm(float x) { return 1.f / (1.f + __expf(-x)); }
__device__ __forceinline__ float tanh_f(float x) { return 1.f - 2.f / (__expf(2.f * x) + 1.f); }

// LLC-direct 16B load (bypass L1+L2). Tracked manually via vmcnt.
#define GLOAD(dst, p) \
    asm volatile("global_load_dwordx4 %0, %1, off sc0 sc1" \
                 : "=v"(dst) : "v"(p))

#define VM_WAIT(n) do { \
    asm volatile("s_waitcnt vmcnt(" #n ")"); \
    __builtin_amdgcn_sched_barrier(0); \
} while (0)

// Write-through store of one f16, bypassing L1 (sc0) and L2 (sc1).
__device__ __forceinline__ void store_f16_wt(_Float16* p, _Float16 v) {
    unsigned short s = __builtin_bit_cast(unsigned short, v);
    unsigned w = s;
    asm volatile("global_store_short %0, %1, off sc0 sc1"
                 :: "v"(p), "v"(w) : "memory");
}

// x-part of the gate GEMM for timestep tt (f16 single-chain).
// Compiler loads: x is read-only and stays L2-resident (no fences).
#define X_PRE(tt, xa)                                                         \
    {                                                                         \
        const float* xrow = xs + ((size_t)rowA * T_ + (size_t)(tt)) * IN_ + kq; \
        _Pragma("unroll")                                                     \
        for (int ks = 0; ks < 16; ++ks) {                                     \
            f4v v0 = *(const f4v*)(xrow + ks * 32);                           \
            f4v v1 = *(const f4v*)(xrow + ks * 32 + 4);                       \
            f16x8 a;                                                          \
            _Pragma("unroll")                                                 \
            for (int j = 0; j < 4; ++j) {                                     \
                a[j]     = (_Float16)v0[j];                                   \
                a[4 + j] = (_Float16)v1[j];                                   \
            }                                                                 \
            f16x8 w = *(const f16x8*)&Wlds[c][ks * 32 + kq];                  \
            xa = __builtin_amdgcn_mfma_f32_16x16x32_f16(a, w, xa, 0, 0, 0);   \
        }                                                                     \
    }

// issue one 8-iter group of gate h loads (8 LLC-direct 16B loads)
#define GISSUE(Areg, kb)                                                      \
    _Pragma("unroll")                                                         \
    for (int i = 0; i < 8; ++i) {                                             \
        GLOAD(Areg[i], hp + ((kb) + i) * 32);                                 \
    }

// consume one 8-iter group (one MFMA per iter, single acc chain)
#define GCONSUME(Areg, kb)                                                    \
    _Pragma("unroll")                                                         \
    for (int i = 0; i < 8; ++i) {                                             \
        f16x8 w = *(const f16x8*)&Wlds[c][IN_ + ((kb) + i) * 32 + kq];        \
        acc = __builtin_amdgcn_mfma_f32_16x16x32_f16(                         \
            __builtin_bit_cast(f16x8, Areg[i]), w, acc, 0, 0, 0);             \
    }

__global__ void __launch_bounds__(256, 1)
lstm_fused(const float* __restrict__ xs, const float* __restrict__ Wi,
           const float* __restrict__ Wh, const float* __restrict__ bias,
           const float* __restrict__ Wo, const float* __restrict__ bo,
           float* __restrict__ out, _Float16* __restrict__ hws,
           unsigned* __restrict__ flags)
{
    __shared__ _Float16 Wlds[16][KTOT + 8];   // 49408 B (f16 weights)
    __shared__ float    gbuf[64][17];         // 4352 B
    __shared__ float    obuf[4][16][17];      // 4352 B   (total 58112 B)

    const int tid = threadIdx.x;
    const int blk = blockIdx.x;       // 0..255
    const int j0  = blk * 4;
    const int ob0 = (blk >> 5) * 8;   // out-proj batch group (8 batches)
    const int oc0 = (blk & 31) * 16;  // out-proj col group (16 cols)

    // Stage resident gate-weight slab (f32 -> f16)
    for (int idx = tid; idx < 16 * KTOT; idx += 256) {
        int k = idx >> 4, c = idx & 15;
        int gc = (c >> 2) * H_ + j0 + (c & 3);
        float w = (k < IN_) ? Wi[(size_t)k * G4_ + gc]
                            : Wh[(size_t)(k - IN_) * G4_ + gc];
        Wlds[c][k] = (_Float16)w;
    }
    __syncthreads();

    const int lane = tid & 63;
    const int wave = tid >> 6;
    const int c    = lane & 15;
    const int quad = lane >> 4;
    const int rowA = wave * 16 + c;   // batch row for gate A-frags
    const int kq   = quad * 8;

    const float biasv = bias[(c >> 2) * H_ + j0 + (c & 3)];

    // Hoist step-invariant Wo fragments into registers (f32 -> f16)
    f16x8 wof[8];
    #pragma unroll
    for (int kk = 0; kk < 8; ++kk) {
        int kbase = wave * 256 + kk * 32 + kq;
        #pragma unroll
        for (int j = 0; j < 8; ++j)
            wof[kk][j] = (_Float16)Wo[(size_t)(kbase + j) * OUT_ + oc0 + c];
    }

    // recurrent cell state: thread owns (batch = tid>>2, j = j0 + (tid&3))
    float c_reg = 0.f;
    const int bb = tid >> 2;
    const int jo = tid & 3;

    // x partial accumulator for the upcoming step (prologue: t=0)
    f4v xacc = {0.f, 0.f, 0.f, 0.f};
    X_PRE(0, xacc);

    const size_t bufsz = (size_t)B_ * H_;   // f16 elems per buffer

    for (int t = 0; t < T_; ++t) {
        asm volatile("" ::: "memory");   // pin loads below the barrier exit
        const int br = (t + 2) % 3;   // buffer holding h_{t-1}
        const int bw = t % 3;         // buffer for h_t
        const _Float16* h_p = hws + (size_t)br * bufsz;
        _Float16*       h_c = hws + (size_t)bw * bufsz;

        // ---- phase A: gate MFMA for step t (x part precomputed) ----
        f4v acc = xacc;
        if (t > 0) {
            const _Float16* hp = h_p + (size_t)rowA * H_ + kq;
            f4v A0[8], A1[8];         // 64 VGPR staging (half of r20's)
            GISSUE(A0, 0);            // G0   [8]
            GISSUE(A1, 8);            // G1   [16]
            VM_WAIT(8);               // G0 retired
            GCONSUME(A0, 0);          // h ks0-7
            GISSUE(A0, 16);           // G2   [16]
            VM_WAIT(8);               // G1 retired
            GCONSUME(A1, 8);          // h ks8-15
            GISSUE(A1, 24);           // G3   [16]
            VM_WAIT(8);               // G2 retired
            GCONSUME(A0, 16);         // h ks16-23
            VM_WAIT(0);               // G3 retired
            GCONSUME(A1, 24);         // h ks24-31
        }
        #pragma unroll
        for (int r = 0; r < 4; ++r)
            gbuf[wave * 16 + quad * 4 + r][c] = acc[r] + biasv;  // C: col=c, row=quad*4+r
        __syncthreads();

        // ---- phase B: elementwise cell update, write h_t (f16, write-through) ----
        {
            float gi = gbuf[bb][jo];
            float gf = gbuf[bb][4 + jo];
            float gg = gbuf[bb][8 + jo];
            float go = gbuf[bb][12 + jo];
            c_reg = sigm(gf) * c_reg + sigm(gi) * tanh_f(gg);
            float hn = sigm(go) * tanh_f(c_reg);
            store_f16_wt(&h_c[(size_t)bb * H_ + j0 + jo], (_Float16)hn);
        }

        // ==== arrive; shadow work; poll (NO fence anywhere) ====
        __syncthreads();   // drains vmcnt: all waves' sc0sc1 h stores ack'd at LLC
        const unsigned tgt = (unsigned)(t + 1);
        if (tid == 0) {
            unsigned* p = &flags[blk * 16];
            asm volatile("global_store_dword %0, %1, off sc0 sc1"
                         :: "v"(p), "v"(tgt) : "memory");
        }

        // ---- shadow 1: out-proj partial for step t-1 (LLC-direct reads).
        // Race-free: buf br next overwritten at step t+2's phase B, which
        // is ordered after barrier(t+1), which needs our flag(t+1), set
        // before this point.
        if (t > 0) {
            f4v Oh[8];
            #pragma unroll
            for (int kk = 0; kk < 8; ++kk)
                Oh[kk] = (f4v){0.f, 0.f, 0.f, 0.f};
            const _Float16* orow = h_p + (size_t)(ob0 + c) * H_;
            if (c < 8) {   // A rows 8..15 zero (8 batches per tile)
                #pragma unroll
                for (int kk = 0; kk < 8; ++kk)
                    GLOAD(Oh[kk], orow + wave * 256 + kk * 32 + kq);
            }
            VM_WAIT(0);
            f4v oac = {0.f, 0.f, 0.f, 0.f};
            #pragma unroll
            for (int kk = 0; kk < 8; ++kk)
                oac = __builtin_amdgcn_mfma_f32_16x16x32_f16(
                    __builtin_bit_cast(f16x8, Oh[kk]), wof[kk], oac, 0, 0, 0);
            #pragma unroll
            for (int r = 0; r < 4; ++r)
                obuf[wave][quad * 4 + r][c] = oac[r];
        }
        __syncthreads();   // obuf visible to reducers (intra-block)

        // ---- shadow 2: reduce out-proj partials, store out[:, t-1, :] ----
        if (t > 0 && tid < 128) {
            int m = tid >> 4, cc = tid & 15;
            float v = obuf[0][m][cc] + obuf[1][m][cc] + obuf[2][m][cc] + obuf[3][m][cc]
                    + bo[oc0 + cc];
            out[(((size_t)(ob0 + m)) * T_ + (t - 1)) * OUT_ + oc0 + cc] = v;
        }

        // ---- shadow 3: x-part of step t+1 (no dependence on h_t) ----
        xacc = (f4v){0.f, 0.f, 0.f, 0.f};
        if (t + 1 < T_) {
            X_PRE(t + 1, xacc);
        }
        asm volatile("" ::: "memory");   // pin shadow loads above the poll

        // ---- wait (relaxed poll; no fence: h readers are LLC-direct) ----
        if (tid < 64) {
            const int lane2 = tid;
            for (;;) {
                unsigned m0 = __hip_atomic_load(&flags[(lane2 * 4 + 0) * 16],
                                                __ATOMIC_RELAXED, __HIP_MEMORY_SCOPE_AGENT);
                unsigned m1 = __hip_atomic_load(&flags[(lane2 * 4 + 1) * 16],
                                                __ATOMIC_RELAXED, __HIP_MEMORY_SCOPE_AGENT);
                unsigned m2 = __hip_atomic_load(&flags[(lane2 * 4 + 2) * 16],
                                                __ATOMIC_RELAXED, __HIP_MEMORY_SCOPE_AGENT);
                unsigned m3 = __hip_atomic_load(&flags[(lane2 * 4 + 3) * 16],
                                                __ATOMIC_RELAXED, __HIP_MEMORY_SCOPE_AGENT);
                bool ok = (m0 >= tgt) & (m1 >= tgt) & (m2 >= tgt) & (m3 >= tgt);
                if (__all(ok)) break;
                __builtin_amdgcn_s_sleep(1);
            }
        }
        __syncthreads();
    }

    // ---- epilogue: out-proj for t = T-1 (h_{T-1} in buf (T-1)%3 = 0) ----
    {
        const _Float16* h_l = hws;            // buf 0
        f4v Oh[8];
        #pragma unroll
        for (int kk = 0; kk < 8; ++kk)
            Oh[kk] = (f4v){0.f, 0.f, 0.f, 0.f};
        const _Float16* orow = h_l + (size_t)(ob0 + c) * H_;
        if (c < 8) {
            #pragma unroll
            for (int kk = 0; kk < 8; ++kk)
                GLOAD(Oh[kk], orow + wave * 256 + kk * 32 + kq);
        }
        VM_WAIT(0);
        f4v oac = {0.f, 0.f, 0.f, 0.f};
        #pragma unroll
        for (int kk = 0; kk < 8; ++kk)
            oac = __builtin_amdgcn_mfma_f32_16x16x32_f16(
                __builtin_bit_cast(f16x8, Oh[kk]), wof[kk], oac, 0, 0, 0);
        #pragma unroll
        for (int r = 0; r < 4; ++r)
            obuf[wave][quad * 4 + r][c] = oac[r];
        __syncthreads();
        if (tid < 128) {
            int m = tid >> 4, cc = tid & 15;
            float v = obuf[0][m][cc] + obuf[1][m][cc] + obuf[2][m][cc] + obuf[3][m][cc]
                    + bo[oc0 + cc];
            out[(((size_t)(ob0 + m)) * T_ + (T_ - 1)) * OUT_ + oc0 + cc] = v;
        }
    }
}

extern "C" void kernel_launch(void* const* d_in, const int* in_sizes, int n_in,
                              void* d_out, int out_size, void* d_ws, size_t ws_size,
                              hipStream_t stream) {
    const float* xs = (const float*)d_in[0];
    const float* Wi = (const float*)d_in[1];
    const float* Wh = (const float*)d_in[2];
    const float* b  = (const float*)d_in[3];
    const float* Wo = (const float*)d_in[4];
    const float* bo = (const float*)d_in[5];
    float* out = (float*)d_out;

    // ws layout: [0,16K) flag vector (256 x 64B-padded, zeroed);
    //            [64K, +384K) h TRIPLE buffer (single f16 plane)
    unsigned*  flags = (unsigned*)d_ws;        // flags[i*16], i = 0..255
    _Float16*  hws   = (_Float16*)((char*)d_ws + 65536);

    hipMemsetAsync(d_ws, 0, 32768, stream);    // reset flags (graph-capture safe)

    void* args[] = {(void*)&xs, (void*)&Wi, (void*)&Wh, (void*)&b,
                    (void*)&Wo, (void*)&bo, (void*)&out, (void*)&hws,
                    (void*)&flags};
    hipLaunchCooperativeKernel((void*)lstm_fused, dim3(256), dim3(256), args, 0, stream);
}

// Round 14
// 3928.950 us; speedup vs baseline: 1.0217x; 1.0217x over previous
//
#include <hip/hip_runtime.h>
#include <hip/hip_cooperative_groups.h>

// LSTM: B=64, T=256, IN=512, H=1024 (4H=4096), OUT=512. I/O f32.
// Round-24 = r23 (f16 datapath, PROVEN, 4014us) with the gate phase
// collapsed to ONE exposed LLC round trip:
//   r23 post-mortem: halving ALL volumes changed nothing -> step time
//   is a chain of ~5-6 serialized LLC round trips (~2-2.5us each under
//   the all-block burst), not bandwidth. r20 beat r23 via deeper issue.
//   This round:
//   1. all 32 gate h loads issued upfront (4 groups x 8; 128 declared
//      staging VGPR = r20's proven envelope), waits 24/16/8/0 -> only
//      the first wait exposes a full round trip.
//   2. dual MFMA acc chains (even/odd ks) halve dependent-MFMA latency
//      in consumption (f32 regroup only; absmax margin 5x).
//   3. first __syncthreads deleted: phase-B threads read ONLY their own
//      wave's gbuf rows (bb=tid>>2 in [w*16,w*16+16) for tid in wave w)
//      -> intra-wave lgkmcnt(0) suffices.
// Everything else r23-verbatim (triple buffer, shadows, flag barrier,
// no fences, LLC-direct h, L2-resident x/weights).
// ws: [0,16K) flags; [64K, +384K) h triple buffer (single f16 plane).

#define B_   64
#define T_   256
#define IN_  512
#define H_   1024
#define G4_  4096
#define OUT_ 512
#define KTOT 1536   // IN_ + H_

typedef _Float16 f16x8 __attribute__((ext_vector_type(8)));
typedef float    f4v   __attribute__((ext_vector_type(4)));

__device__ __forceinline__ float sigm(float x) { return 1.f / (1.f + __expf(-x)); }
__device__ __forceinline__ float tanh_f(float x) { return 1.f - 2.f / (__expf(2.f * x) + 1.f); }

// LLC-direct 16B load (bypass L1+L2). Tracked manually via vmcnt.
#define GLOAD(dst, p) \
    asm volatile("global_load_dwordx4 %0, %1, off sc0 sc1" \
                 : "=v"(dst) : "v"(p))

#define VM_WAIT(n) do { \
    asm volatile("s_waitcnt vmcnt(" #n ")"); \
    __builtin_amdgcn_sched_barrier(0); \
} while (0)

// Write-through store of one f16, bypassing L1 (sc0) and L2 (sc1).
__device__ __forceinline__ void store_f16_wt(_Float16* p, _Float16 v) {
    unsigned short s = __builtin_bit_cast(unsigned short, v);
    unsigned w = s;
    asm volatile("global_store_short %0, %1, off sc0 sc1"
                 :: "v"(p), "v"(w) : "memory");
}

// x-part of the gate GEMM for timestep tt (f16 single-chain).
// Compiler loads: x is read-only and stays L2-resident (no fences).
#define X_PRE(tt, xa)                                                         \
    {                                                                         \
        const float* xrow = xs + ((size_t)rowA * T_ + (size_t)(tt)) * IN_ + kq; \
        _Pragma("unroll")                                                     \
        for (int ks = 0; ks < 16; ++ks) {                                     \
            f4v v0 = *(const f4v*)(xrow + ks * 32);                           \
            f4v v1 = *(const f4v*)(xrow + ks * 32 + 4);                       \
            f16x8 a;                                                          \
            _Pragma("unroll")                                                 \
            for (int j = 0; j < 4; ++j) {                                     \
                a[j]     = (_Float16)v0[j];                                   \
                a[4 + j] = (_Float16)v1[j];                                   \
            }                                                                 \
            f16x8 w = *(const f16x8*)&Wlds[c][ks * 32 + kq];                  \
            xa = __builtin_amdgcn_mfma_f32_16x16x32_f16(a, w, xa, 0, 0, 0);   \
        }                                                                     \
    }

// issue one 8-iter group of gate h loads (8 LLC-direct 16B loads)
#define GISSUE(Areg, kb)                                                      \
    _Pragma("unroll")                                                         \
    for (int i = 0; i < 8; ++i) {                                             \
        GLOAD(Areg[i], hp + ((kb) + i) * 32);                                 \
    }

// consume one 8-iter group; even ks -> acc, odd ks -> acc2 (dual chains)
#define GCONSUME(Areg, kb)                                                    \
    _Pragma("unroll")                                                         \
    for (int i = 0; i < 8; ++i) {                                             \
        f16x8 w = *(const f16x8*)&Wlds[c][IN_ + ((kb) + i) * 32 + kq];        \
        if (i & 1)                                                            \
            acc2 = __builtin_amdgcn_mfma_f32_16x16x32_f16(                    \
                __builtin_bit_cast(f16x8, Areg[i]), w, acc2, 0, 0, 0);        \
        else                                                                  \
            acc = __builtin_amdgcn_mfma_f32_16x16x32_f16(                     \
                __builtin_bit_cast(f16x8, Areg[i]), w, acc, 0, 0, 0);         \
    }

__global__ void __launch_bounds__(256, 1)
lstm_fused(const float* __restrict__ xs, const float* __restrict__ Wi,
           const float* __restrict__ Wh, const float* __restrict__ bias,
           const float* __restrict__ Wo, const float* __restrict__ bo,
           float* __restrict__ out, _Float16* __restrict__ hws,
           unsigned* __restrict__ flags)
{
    __shared__ _Float16 Wlds[16][KTOT + 8];   // 49408 B (f16 weights)
    __shared__ float    gbuf[64][17];         // 4352 B
    __shared__ float    obuf[4][16][17];      // 4352 B   (total 58112 B)

    const int tid = threadIdx.x;
    const int blk = blockIdx.x;       // 0..255
    const int j0  = blk * 4;
    const int ob0 = (blk >> 5) * 8;   // out-proj batch group (8 batches)
    const int oc0 = (blk & 31) * 16;  // out-proj col group (16 cols)

    // Stage resident gate-weight slab (f32 -> f16)
    for (int idx = tid; idx < 16 * KTOT; idx += 256) {
        int k = idx >> 4, c = idx & 15;
        int gc = (c >> 2) * H_ + j0 + (c & 3);
        float w = (k < IN_) ? Wi[(size_t)k * G4_ + gc]
                            : Wh[(size_t)(k - IN_) * G4_ + gc];
        Wlds[c][k] = (_Float16)w;
    }
    __syncthreads();

    const int lane = tid & 63;
    const int wave = tid >> 6;
    const int c    = lane & 15;
    const int quad = lane >> 4;
    const int rowA = wave * 16 + c;   // batch row for gate A-frags
    const int kq   = quad * 8;

    const float biasv = bias[(c >> 2) * H_ + j0 + (c & 3)];

    // Hoist step-invariant Wo fragments into registers (f32 -> f16)
    f16x8 wof[8];
    #pragma unroll
    for (int kk = 0; kk < 8; ++kk) {
        int kbase = wave * 256 + kk * 32 + kq;
        #pragma unroll
        for (int j = 0; j < 8; ++j)
            wof[kk][j] = (_Float16)Wo[(size_t)(kbase + j) * OUT_ + oc0 + c];
    }

    // recurrent cell state: thread owns (batch = tid>>2, j = j0 + (tid&3))
    float c_reg = 0.f;
    const int bb = tid >> 2;
    const int jo = tid & 3;

    // x partial accumulator for the upcoming step (prologue: t=0)
    f4v xacc = {0.f, 0.f, 0.f, 0.f};
    X_PRE(0, xacc);

    const size_t bufsz = (size_t)B_ * H_;   // f16 elems per buffer

    for (int t = 0; t < T_; ++t) {
        asm volatile("" ::: "memory");   // pin loads below the barrier exit
        const int br = (t + 2) % 3;   // buffer holding h_{t-1}
        const int bw = t % 3;         // buffer for h_t
        const _Float16* h_p = hws + (size_t)br * bufsz;
        _Float16*       h_c = hws + (size_t)bw * bufsz;

        // ---- phase A: gate MFMA for step t (x part precomputed) ----
        f4v acc  = xacc;
        f4v acc2 = {0.f, 0.f, 0.f, 0.f};
        if (t > 0) {
            const _Float16* hp = h_p + (size_t)rowA * H_ + kq;
            f4v A0[8], A1[8], A2r[8], A3[8];   // 128 VGPR declared staging
            GISSUE(A0, 0);            // [8]
            GISSUE(A1, 8);            // [16]
            GISSUE(A2r, 16);          // [24]
            GISSUE(A3, 24);           // [32] all in flight
            VM_WAIT(24);              // G0 retired (one exposed round trip)
            GCONSUME(A0, 0);
            VM_WAIT(16);              // G1 retired (pipeline-behind)
            GCONSUME(A1, 8);
            VM_WAIT(8);               // G2 retired
            GCONSUME(A2r, 16);
            VM_WAIT(0);               // G3 retired
            GCONSUME(A3, 24);
        }
        acc += acc2;
        #pragma unroll
        for (int r = 0; r < 4; ++r)
            gbuf[wave * 16 + quad * 4 + r][c] = acc[r] + biasv;  // C: col=c, row=quad*4+r
        // NO __syncthreads here: phase B reads only THIS wave's gbuf rows.
        asm volatile("s_waitcnt lgkmcnt(0)");
        __builtin_amdgcn_sched_barrier(0);

        // ---- phase B: elementwise cell update, write h_t (f16, write-through) ----
        {
            float gi = gbuf[bb][jo];
            float gf = gbuf[bb][4 + jo];
            float gg = gbuf[bb][8 + jo];
            float go = gbuf[bb][12 + jo];
            c_reg = sigm(gf) * c_reg + sigm(gi) * tanh_f(gg);
            float hn = sigm(go) * tanh_f(c_reg);
            store_f16_wt(&h_c[(size_t)bb * H_ + j0 + jo], (_Float16)hn);
        }

        // ==== arrive; shadow work; poll (NO fence anywhere) ====
        __syncthreads();   // drains vmcnt: all waves' sc0sc1 h stores ack'd at LLC
        const unsigned tgt = (unsigned)(t + 1);
        if (tid == 0) {
            unsigned* p = &flags[blk * 16];
            asm volatile("global_store_dword %0, %1, off sc0 sc1"
                         :: "v"(p), "v"(tgt) : "memory");
        }

        // ---- shadow 1: out-proj partial for step t-1 (LLC-direct reads).
        // Race-free: buf br next overwritten at step t+2's phase B, which
        // is ordered after barrier(t+1), which needs our flag(t+1), set
        // before this point.
        if (t > 0) {
            f4v Oh[8];
            #pragma unroll
            for (int kk = 0; kk < 8; ++kk)
                Oh[kk] = (f4v){0.f, 0.f, 0.f, 0.f};
            const _Float16* orow = h_p + (size_t)(ob0 + c) * H_;
            if (c < 8) {   // A rows 8..15 zero (8 batches per tile)
                #pragma unroll
                for (int kk = 0; kk < 8; ++kk)
                    GLOAD(Oh[kk], orow + wave * 256 + kk * 32 + kq);
            }
            VM_WAIT(0);
            f4v oac = {0.f, 0.f, 0.f, 0.f};
            #pragma unroll
            for (int kk = 0; kk < 8; ++kk)
                oac = __builtin_amdgcn_mfma_f32_16x16x32_f16(
                    __builtin_bit_cast(f16x8, Oh[kk]), wof[kk], oac, 0, 0, 0);
            #pragma unroll
            for (int r = 0; r < 4; ++r)
                obuf[wave][quad * 4 + r][c] = oac[r];
        }
        __syncthreads();   // obuf visible to reducers (intra-block)

        // ---- shadow 2: reduce out-proj partials, store out[:, t-1, :] ----
        if (t > 0 && tid < 128) {
            int m = tid >> 4, cc = tid & 15;
            float v = obuf[0][m][cc] + obuf[1][m][cc] + obuf[2][m][cc] + obuf[3][m][cc]
                    + bo[oc0 + cc];
            out[(((size_t)(ob0 + m)) * T_ + (t - 1)) * OUT_ + oc0 + cc] = v;
        }

        // ---- shadow 3: x-part of step t+1 (no dependence on h_t) ----
        xacc = (f4v){0.f, 0.f, 0.f, 0.f};
        if (t + 1 < T_) {
            X_PRE(t + 1, xacc);
        }
        asm volatile("" ::: "memory");   // pin shadow loads above the poll

        // ---- wait (relaxed poll; no fence: h readers are LLC-direct) ----
        if (tid < 64) {
            const int lane2 = tid;
            for (;;) {
                unsigned m0 = __hip_atomic_load(&flags[(lane2 * 4 + 0) * 16],
                                                __ATOMIC_RELAXED, __HIP_MEMORY_SCOPE_AGENT);
                unsigned m1 = __hip_atomic_load(&flags[(lane2 * 4 + 1) * 16],
                                                __ATOMIC_RELAXED, __HIP_MEMORY_SCOPE_AGENT);
                unsigned m2 = __hip_atomic_load(&flags[(lane2 * 4 + 2) * 16],
                                                __ATOMIC_RELAXED, __HIP_MEMORY_SCOPE_AGENT);
                unsigned m3 = __hip_atomic_load(&flags[(lane2 * 4 + 3) * 16],
                                                __ATOMIC_RELAXED, __HIP_MEMORY_SCOPE_AGENT);
                bool ok = (m0 >= tgt) & (m1 >= tgt) & (m2 >= tgt) & (m3 >= tgt);
                if (__all(ok)) break;
                __builtin_amdgcn_s_sleep(1);
            }
        }
        __syncthreads();
    }

    // ---- epilogue: out-proj for t = T-1 (h_{T-1} in buf (T-1)%3 = 0) ----
    {
        const _Float16* h_l = hws;            // buf 0
        f4v Oh[8];
        #pragma unroll
        for (int kk = 0; kk < 8; ++kk)
            Oh[kk] = (f4v){0.f, 0.f, 0.f, 0.f};
        const _Float16* orow = h_l + (size_t)(ob0 + c) * H_;
        if (c < 8) {
            #pragma unroll
            for (int kk = 0; kk < 8; ++kk)
                GLOAD(Oh[kk], orow + wave * 256 + kk * 32 + kq);
        }
        VM_WAIT(0);
        f4v oac = {0.f, 0.f, 0.f, 0.f};
        #pragma unroll
        for (int kk = 0; kk < 8; ++kk)
            oac = __builtin_amdgcn_mfma_f32_16x16x32_f16(
                __builtin_bit_cast(f16x8, Oh[kk]), wof[kk], oac, 0, 0, 0);
        #pragma unroll
        for (int r = 0; r < 4; ++r)
            obuf[wave][quad * 4 + r][c] = oac[r];
        __syncthreads();
        if (tid < 128) {
            int m = tid >> 4, cc = tid & 15;
            float v = obuf[0][m][cc] + obuf[1][m][cc] + obuf[2][m][cc] + obuf[3][m][cc]
                    + bo[oc0 + cc];
            out[(((size_t)(ob0 + m)) * T_ + (T_ - 1)) * OUT_ + oc0 + cc] = v;
        }
    }
}

extern "C" void kernel_launch(void* const* d_in, const int* in_sizes, int n_in,
                              void* d_out, int out_size, void* d_ws, size_t ws_size,
                              hipStream_t stream) {
    const float* xs = (const float*)d_in[0];
    const float* Wi = (const float*)d_in[1];
    const float* Wh = (const float*)d_in[2];
    const float* b  = (const float*)d_in[3];
    const float* Wo = (const float*)d_in[4];
    const float* bo = (const float*)d_in[5];
    float* out = (float*)d_out;

    // ws layout: [0,16K) flag vector (256 x 64B-padded, zeroed);
    //            [64K, +384K) h TRIPLE buffer (single f16 plane)
    unsigned*  flags = (unsigned*)d_ws;        // flags[i*16], i = 0..255
    _Float16*  hws   = (_Float16*)((char*)d_ws + 65536);

    hipMemsetAsync(d_ws, 0, 32768, stream);    // reset flags (graph-capture safe)

    void* args[] = {(void*)&xs, (void*)&Wi, (void*)&Wh, (void*)&b,
                    (void*)&Wo, (void*)&bo, (void*)&out, (void*)&hws,
                    (void*)&flags};
    hipLaunchCooperativeKernel((void*)lstm_fused, dim3(256), dim3(256), args, 0, stream);
}

// Round 15
// 3887.715 us; speedup vs baseline: 1.0325x; 1.0106x over previous
//
#include <hip/hip_runtime.h>
#include <hip/hip_cooperative_groups.h>

// LSTM: B=64, T=256, IN=512, H=1024 (4H=4096), OUT=512. I/O f32.
// Round-25 = r24 (f16, 3929us) with the A2 (out-proj) h-loads MERGED
// into the gate-phase issue burst, deleting shadow-1's exposed
// vmcnt(0) LLC round trip (~1-1.5us/step):
//   r24 post-mortem: VGPR_Count=104 < 128 declared staging -> the
//   allocator spilled part of the "all-upfront" burst; safe envelope
//   for ONE counted region is <=128 declared VGPRs (r20/r23/r24 all
//   pass there; r21/r22 at 192/320 both failed via spill-shifted
//   retire-order <-> count mapping).
//   This round's gate region: G0,G1,G2 (96) + O (32) = exactly 128.
//   G3 reuses G0's registers (r20's proven rotation). Issue order
//   G0,G1,G2,O -> waits: 24[G0] (issue G3) -> 24[G1] -> 16[G2] ->
//   0[O+G3]. Oh[] is held across phase B / the arrive-sync; by
//   shadow-1 the pre-arrive __syncthreads has drained vmcnt, so the
//   out-proj MFMAs run with NO wait and NO loads.
// Everything else r24-verbatim: f16 datapath, dual gate acc chains,
// no first syncthreads (phase B reads only own wave's gbuf rows),
// triple h buffer, flag barrier, no fences, LLC-direct h, L2-resident
// x/weights.
// ws: [0,16K) flags; [64K, +384K) h triple buffer (single f16 plane).

#define B_   64
#define T_   256
#define IN_  512
#define H_   1024
#define G4_  4096
#define OUT_ 512
#define KTOT 1536   // IN_ + H_

typedef _Float16 f16x8 __attribute__((ext_vector_type(8)));
typedef float    f4v   __attribute__((ext_vector_type(4)));

__device__ __forceinline__ float sigm(float x) { return 1.f / (1.f + __expf(-x)); }
__device__ __forceinline__ float tanh_f(float x) { return 1.f - 2.f / (__expf(2.f * x) + 1.f); }

// LLC-direct 16B load (bypass L1+L2). Tracked manually via vmcnt.
#define GLOAD(dst, p) \
    asm volatile("global_load_dwordx4 %0, %1, off sc0 sc1" \
                 : "=v"(dst) : "v"(p))

#define VM_WAIT(n) do { \
    asm volatile("s_waitcnt vmcnt(" #n ")"); \
    __builtin_amdgcn_sched_barrier(0); \
} while (0)

// Write-through store of one f16, bypassing L1 (sc0) and L2 (sc1).
__device__ __forceinline__ void store_f16_wt(_Float16* p, _Float16 v) {
    unsigned short s = __builtin_bit_cast(unsigned short, v);
    unsigned w = s;
    asm volatile("global_store_short %0, %1, off sc0 sc1"
                 :: "v"(p), "v"(w) : "memory");
}

// x-part of the gate GEMM for timestep tt (f16 single-chain).
// Compiler loads: x is read-only and stays L2-resident (no fences).
#define X_PRE(tt, xa)                                                         \
    {                                                                         \
        const float* xrow = xs + ((size_t)rowA * T_ + (size_t)(tt)) * IN_ + kq; \
        _Pragma("unroll")                                                     \
        for (int ks = 0; ks < 16; ++ks) {                                     \
            f4v v0 = *(const f4v*)(xrow + ks * 32);                           \
            f4v v1 = *(const f4v*)(xrow + ks * 32 + 4);                       \
            f16x8 a;                                                          \
            _Pragma("unroll")                                                 \
            for (int j = 0; j < 4; ++j) {                                     \
                a[j]     = (_Float16)v0[j];                                   \
                a[4 + j] = (_Float16)v1[j];                                   \
            }                                                                 \
            f16x8 w = *(const f16x8*)&Wlds[c][ks * 32 + kq];                  \
            xa = __builtin_amdgcn_mfma_f32_16x16x32_f16(a, w, xa, 0, 0, 0);   \
        }                                                                     \
    }

// issue one 8-iter group of gate h loads (8 LLC-direct 16B loads)
#define GISSUE(Areg, kb)                                                      \
    _Pragma("unroll")                                                         \
    for (int i = 0; i < 8; ++i) {                                             \
        GLOAD(Areg[i], hp + ((kb) + i) * 32);                                 \
    }

// consume one 8-iter group; even ks -> acc, odd ks -> acc2 (dual chains)
#define GCONSUME(Areg, kb)                                                    \
    _Pragma("unroll")                                                         \
    for (int i = 0; i < 8; ++i) {                                             \
        f16x8 w = *(const f16x8*)&Wlds[c][IN_ + ((kb) + i) * 32 + kq];        \
        if (i & 1)                                                            \
            acc2 = __builtin_amdgcn_mfma_f32_16x16x32_f16(                    \
                __builtin_bit_cast(f16x8, Areg[i]), w, acc2, 0, 0, 0);        \
        else                                                                  \
            acc = __builtin_amdgcn_mfma_f32_16x16x32_f16(                     \
                __builtin_bit_cast(f16x8, Areg[i]), w, acc, 0, 0, 0);         \
    }

__global__ void __launch_bounds__(256, 1)
lstm_fused(const float* __restrict__ xs, const float* __restrict__ Wi,
           const float* __restrict__ Wh, const float* __restrict__ bias,
           const float* __restrict__ Wo, const float* __restrict__ bo,
           float* __restrict__ out, _Float16* __restrict__ hws,
           unsigned* __restrict__ flags)
{
    __shared__ _Float16 Wlds[16][KTOT + 8];   // 49408 B (f16 weights)
    __shared__ float    gbuf[64][17];         // 4352 B
    __shared__ float    obuf[4][16][17];      // 4352 B   (total 58112 B)

    const int tid = threadIdx.x;
    const int blk = blockIdx.x;       // 0..255
    const int j0  = blk * 4;
    const int ob0 = (blk >> 5) * 8;   // out-proj batch group (8 batches)
    const int oc0 = (blk & 31) * 16;  // out-proj col group (16 cols)

    // Stage resident gate-weight slab (f32 -> f16)
    for (int idx = tid; idx < 16 * KTOT; idx += 256) {
        int k = idx >> 4, c = idx & 15;
        int gc = (c >> 2) * H_ + j0 + (c & 3);
        float w = (k < IN_) ? Wi[(size_t)k * G4_ + gc]
                            : Wh[(size_t)(k - IN_) * G4_ + gc];
        Wlds[c][k] = (_Float16)w;
    }
    __syncthreads();

    const int lane = tid & 63;
    const int wave = tid >> 6;
    const int c    = lane & 15;
    const int quad = lane >> 4;
    const int rowA = wave * 16 + c;   // batch row for gate A-frags
    const int kq   = quad * 8;

    const float biasv = bias[(c >> 2) * H_ + j0 + (c & 3)];

    // Hoist step-invariant Wo fragments into registers (f32 -> f16)
    f16x8 wof[8];
    #pragma unroll
    for (int kk = 0; kk < 8; ++kk) {
        int kbase = wave * 256 + kk * 32 + kq;
        #pragma unroll
        for (int j = 0; j < 8; ++j)
            wof[kk][j] = (_Float16)Wo[(size_t)(kbase + j) * OUT_ + oc0 + c];
    }

    // recurrent cell state: thread owns (batch = tid>>2, j = j0 + (tid&3))
    float c_reg = 0.f;
    const int bb = tid >> 2;
    const int jo = tid & 3;

    // x partial accumulator for the upcoming step (prologue: t=0)
    f4v xacc = {0.f, 0.f, 0.f, 0.f};
    X_PRE(0, xacc);

    const size_t bufsz = (size_t)B_ * H_;   // f16 elems per buffer

    for (int t = 0; t < T_; ++t) {
        asm volatile("" ::: "memory");   // pin loads below the barrier exit
        const int br = (t + 2) % 3;   // buffer holding h_{t-1}
        const int bw = t % 3;         // buffer for h_t
        const _Float16* h_p = hws + (size_t)br * bufsz;
        _Float16*       h_c = hws + (size_t)bw * bufsz;

        // ---- phase A: gate MFMA for step t (x part precomputed);
        //      A2's 8 h-loads ride in the same issue burst ----
        f4v acc  = xacc;
        f4v acc2 = {0.f, 0.f, 0.f, 0.f};
        f4v Oh[8];   // out-proj A-frags: loaded here, consumed in shadow-1
        #pragma unroll
        for (int kk = 0; kk < 8; ++kk)
            Oh[kk] = (f4v){0.f, 0.f, 0.f, 0.f};
        if (t > 0) {
            const _Float16* hp   = h_p + (size_t)rowA * H_ + kq;
            const _Float16* orow = h_p + (size_t)(ob0 + c) * H_;
            f4v A0[8], A1[8], A2r[8];   // 96 + Oh 32 = 128 declared (proven cap)
            GISSUE(A0, 0);            // G0 [8]
            GISSUE(A1, 8);            // G1 [16]
            GISSUE(A2r, 16);          // G2 [24]
            if (c < 8) {              // O  [32] (every wave has c<8 lanes ->
                #pragma unroll        //  uniform per-wave vmcnt)
                for (int kk = 0; kk < 8; ++kk)
                    GLOAD(Oh[kk], orow + wave * 256 + kk * 32 + kq);
            }
            VM_WAIT(24);              // G0 retired (one exposed round trip)
            GCONSUME(A0, 0);
            GISSUE(A0, 24);           // G3 into G0's registers [32]
            VM_WAIT(24);              // G1 retired
            GCONSUME(A1, 8);
            VM_WAIT(16);              // G2 retired
            GCONSUME(A2r, 16);
            VM_WAIT(0);               // O + G3 retired
            GCONSUME(A0, 24);
        }
        acc += acc2;
        #pragma unroll
        for (int r = 0; r < 4; ++r)
            gbuf[wave * 16 + quad * 4 + r][c] = acc[r] + biasv;  // C: col=c, row=quad*4+r
        // NO __syncthreads here: phase B reads only THIS wave's gbuf rows.
        asm volatile("s_waitcnt lgkmcnt(0)");
        __builtin_amdgcn_sched_barrier(0);

        // ---- phase B: elementwise cell update, write h_t (f16, write-through) ----
        {
            float gi = gbuf[bb][jo];
            float gf = gbuf[bb][4 + jo];
            float gg = gbuf[bb][8 + jo];
            float go = gbuf[bb][12 + jo];
            c_reg = sigm(gf) * c_reg + sigm(gi) * tanh_f(gg);
            float hn = sigm(go) * tanh_f(c_reg);
            store_f16_wt(&h_c[(size_t)bb * H_ + j0 + jo], (_Float16)hn);
        }

        // ==== arrive; shadow work; poll (NO fence anywhere) ====
        __syncthreads();   // drains vmcnt: all waves' sc0sc1 h stores ack'd at LLC
        const unsigned tgt = (unsigned)(t + 1);
        if (tid == 0) {
            unsigned* p = &flags[blk * 16];
            asm volatile("global_store_dword %0, %1, off sc0 sc1"
                         :: "v"(p), "v"(tgt) : "memory");
        }

        // ---- shadow 1: out-proj MFMAs for step t-1. Loads were issued in
        // phase A and drained by the arrive-sync: NO wait, NO loads here.
        // Race-free: buf br next overwritten at step t+2's phase B, ordered
        // after barrier(t+1), which needs our flag(t+1), set above.
        if (t > 0) {
            f4v oac = {0.f, 0.f, 0.f, 0.f};
            #pragma unroll
            for (int kk = 0; kk < 8; ++kk)
                oac = __builtin_amdgcn_mfma_f32_16x16x32_f16(
                    __builtin_bit_cast(f16x8, Oh[kk]), wof[kk], oac, 0, 0, 0);
            #pragma unroll
            for (int r = 0; r < 4; ++r)
                obuf[wave][quad * 4 + r][c] = oac[r];
        }
        __syncthreads();   // obuf visible to reducers (intra-block)

        // ---- shadow 2: reduce out-proj partials, store out[:, t-1, :] ----
        if (t > 0 && tid < 128) {
            int m = tid >> 4, cc = tid & 15;
            float v = obuf[0][m][cc] + obuf[1][m][cc] + obuf[2][m][cc] + obuf[3][m][cc]
                    + bo[oc0 + cc];
            out[(((size_t)(ob0 + m)) * T_ + (t - 1)) * OUT_ + oc0 + cc] = v;
        }

        // ---- shadow 3: x-part of step t+1 (no dependence on h_t) ----
        xacc = (f4v){0.f, 0.f, 0.f, 0.f};
        if (t + 1 < T_) {
            X_PRE(t + 1, xacc);
        }
        asm volatile("" ::: "memory");   // pin shadow loads above the poll

        // ---- wait (relaxed poll; no fence: h readers are LLC-direct) ----
        if (tid < 64) {
            const int lane2 = tid;
            for (;;) {
                unsigned m0 = __hip_atomic_load(&flags[(lane2 * 4 + 0) * 16],
                                                __ATOMIC_RELAXED, __HIP_MEMORY_SCOPE_AGENT);
                unsigned m1 = __hip_atomic_load(&flags[(lane2 * 4 + 1) * 16],
                                                __ATOMIC_RELAXED, __HIP_MEMORY_SCOPE_AGENT);
                unsigned m2 = __hip_atomic_load(&flags[(lane2 * 4 + 2) * 16],
                                                __ATOMIC_RELAXED, __HIP_MEMORY_SCOPE_AGENT);
                unsigned m3 = __hip_atomic_load(&flags[(lane2 * 4 + 3) * 16],
                                                __ATOMIC_RELAXED, __HIP_MEMORY_SCOPE_AGENT);
                bool ok = (m0 >= tgt) & (m1 >= tgt) & (m2 >= tgt) & (m3 >= tgt);
                if (__all(ok)) break;
                __builtin_amdgcn_s_sleep(1);
            }
        }
        __syncthreads();
    }

    // ---- epilogue: out-proj for t = T-1 (h_{T-1} in buf (T-1)%3 = 0) ----
    {
        const _Float16* h_l = hws;            // buf 0
        f4v Oh[8];
        #pragma unroll
        for (int kk = 0; kk < 8; ++kk)
            Oh[kk] = (f4v){0.f, 0.f, 0.f, 0.f};
        const _Float16* orow = h_l + (size_t)(ob0 + c) * H_;
        if (c < 8) {
            #pragma unroll
            for (int kk = 0; kk < 8; ++kk)
                GLOAD(Oh[kk], orow + wave * 256 + kk * 32 + kq);
        }
        VM_WAIT(0);
        f4v oac = {0.f, 0.f, 0.f, 0.f};
        #pragma unroll
        for (int kk = 0; kk < 8; ++kk)
            oac = __builtin_amdgcn_mfma_f32_16x16x32_f16(
                __builtin_bit_cast(f16x8, Oh[kk]), wof[kk], oac, 0, 0, 0);
        #pragma unroll
        for (int r = 0; r < 4; ++r)
            obuf[wave][quad * 4 + r][c] = oac[r];
        __syncthreads();
        if (tid < 128) {
            int m = tid >> 4, cc = tid & 15;
            float v = obuf[0][m][cc] + obuf[1][m][cc] + obuf[2][m][cc] + obuf[3][m][cc]
                    + bo[oc0 + cc];
            out[(((size_t)(ob0 + m)) * T_ + (T_ - 1)) * OUT_ + oc0 + cc] = v;
        }
    }
}

extern "C" void kernel_launch(void* const* d_in, const int* in_sizes, int n_in,
                              void* d_out, int out_size, void* d_ws, size_t ws_size,
                              hipStream_t stream) {
    const float* xs = (const float*)d_in[0];
    const float* Wi = (const float*)d_in[1];
    const float* Wh = (const float*)d_in[2];
    const float* b  = (const float*)d_in[3];
    const float* Wo = (const float*)d_in[4];
    const float* bo = (const float*)d_in[5];
    float* out = (float*)d_out;

    // ws layout: [0,16K) flag vector (256 x 64B-padded, zeroed);
    //            [64K, +384K) h TRIPLE buffer (single f16 plane)
    unsigned*  flags = (unsigned*)d_ws;        // flags[i*16], i = 0..255
    _Float16*  hws   = (_Float16*)((char*)d_ws + 65536);

    hipMemsetAsync(d_ws, 0, 32768, stream);    // reset flags (graph-capture safe)

    void* args[] = {(void*)&xs, (void*)&Wi, (void*)&Wh, (void*)&b,
                    (void*)&Wo, (void*)&bo, (void*)&out, (void*)&hws,
                    (void*)&flags};
    hipLaunchCooperativeKernel((void*)lstm_fused, dim3(256), dim3(256), args, 0, stream);
}

// Round 17
// 3738.797 us; speedup vs baseline: 1.0737x; 1.0398x over previous
//
#include <hip/hip_runtime.h>
#include <hip/hip_cooperative_groups.h>

// LSTM: B=64, T=256, IN=512, H=1024 (4H=4096), OUT=512. I/O f32.
// Round-27 = r20 VERBATIM (3768us champion: bf16 hi/lo, LLC-direct h,
// no fences, counted vmcnt, triple buffer, shadowed A2/B2/x) with ONE
// safe change: the phase-A -> phase-B __syncthreads is deleted
// (phase B thread tid reads ONLY gbuf row tid>>2, which lies in
// [16w,16w+16) for wave w = tid>>6 — written by the SAME wave;
// lgkmcnt(0)+sched_barrier suffices). Pattern validated in r24/r25.
//   META (r15/r16/r21/r22/r26 post-mortem): absmax 1.0703125 is the
//   STUB value (out==0) -> all five were LAUNCH FAILURES, not compute
//   bugs. Cliff: >=192 declared asm-staging VGPRs, >64KB LDS, or
//   launch-time attribute calls kill the cooperative launch. Rules:
//   <=128 declared staging, <=64KB static LDS, no attr calls.
// Coherence (r20-proven): h stores sc0sc1 -> vmcnt drain at arrive
// syncthreads -> flag store sc0sc1 -> relaxed poll -> LLC-direct reads.
// NO fences. x/weights stay L2-resident.
// ws: [0,16K) flags; [64K, +768K) h triple buffer (hi/lo planes).

#define B_   64
#define T_   256
#define IN_  512
#define H_   1024
#define G4_  4096
#define OUT_ 512
#define KTOT 1536   // IN_ + H_

typedef __bf16 bf8v  __attribute__((ext_vector_type(8)));
typedef float  f4v   __attribute__((ext_vector_type(4)));

__device__ __forceinline__ float sigm(float x) { return 1.f / (1.f + __expf(-x)); }
__device__ __forceinline__ float tanh_f(float x) { return 1.f - 2.f / (__expf(2.f * x) + 1.f); }

// LLC-direct 16B load (bypass L1+L2). Tracked manually via vmcnt.
#define GLOAD(dst, p) \
    asm volatile("global_load_dwordx4 %0, %1, off sc0 sc1" \
                 : "=v"(dst) : "v"(p))

#define VM_WAIT(n) do { \
    asm volatile("s_waitcnt vmcnt(" #n ")"); \
    __builtin_amdgcn_sched_barrier(0); \
} while (0)

// Write-through store of one bf16, bypassing L1 (sc0) and L2 (sc1).
__device__ __forceinline__ void store_bf16_wt(__bf16* p, __bf16 v) {
    union { __bf16 b; unsigned short s; } cv; cv.b = v;
    unsigned w = cv.s;
    asm volatile("global_store_short %0, %1, off sc0 sc1"
                 :: "v"(p), "v"(w) : "memory");
}

// x-part of the gate GEMM for timestep tt (r12 order). Plain cached
// loads: x is read-only and, with no invalidates, stays L2-resident.
#define X_PRE(tt, xa0, xa1)                                                   \
    {                                                                         \
        const float* xrow = xs + ((size_t)rowA * T_ + (size_t)(tt)) * IN_ + kq; \
        _Pragma("unroll")                                                     \
        for (int ks = 0; ks < 16; ++ks) {                                     \
            f4v v0 = *(const f4v*)(xrow + ks * 32);                           \
            f4v v1 = *(const f4v*)(xrow + ks * 32 + 4);                       \
            bf8v ah, al;                                                      \
            _Pragma("unroll")                                                 \
            for (int j = 0; j < 4; ++j) {                                     \
                __bf16 h0 = (__bf16)v0[j], h1 = (__bf16)v1[j];                \
                ah[j] = h0;  ah[4 + j] = h1;                                  \
                al[j]     = (__bf16)(v0[j] - (float)h0);                      \
                al[4 + j] = (__bf16)(v1[j] - (float)h1);                      \
            }                                                                 \
            bf8v w = *(const bf8v*)&Wlds[c][ks * 32 + kq];                    \
            xa0 = __builtin_amdgcn_mfma_f32_16x16x32_bf16(ah, w, xa0, 0, 0, 0); \
            xa1 = __builtin_amdgcn_mfma_f32_16x16x32_bf16(al, w, xa1, 0, 0, 0); \
        }                                                                     \
    }

// issue one 8-iter group of gate h loads (16 LLC-direct loads)
#define GISSUE(Hreg, Lreg, kb)                                                \
    _Pragma("unroll")                                                         \
    for (int i = 0; i < 8; ++i) {                                             \
        GLOAD(Hreg[i], hh + ((kb) + i) * 32);                                 \
        GLOAD(Lreg[i], hl + ((kb) + i) * 32);                                 \
    }

// consume one 8-iter group (order identical to r12's ks sweep)
#define GCONSUME(Hreg, Lreg, kb)                                              \
    _Pragma("unroll")                                                         \
    for (int i = 0; i < 8; ++i) {                                             \
        bf8v w = *(const bf8v*)&Wlds[c][IN_ + ((kb) + i) * 32 + kq];          \
        acc0 = __builtin_amdgcn_mfma_f32_16x16x32_bf16(                       \
            __builtin_bit_cast(bf8v, Hreg[i]), w, acc0, 0, 0, 0);             \
        acc1 = __builtin_amdgcn_mfma_f32_16x16x32_bf16(                       \
            __builtin_bit_cast(bf8v, Lreg[i]), w, acc1, 0, 0, 0);             \
    }

__global__ void __launch_bounds__(256, 1)
lstm_fused(const float* __restrict__ xs, const float* __restrict__ Wi,
           const float* __restrict__ Wh, const float* __restrict__ bias,
           const float* __restrict__ Wo, const float* __restrict__ bo,
           float* __restrict__ out, __bf16* __restrict__ hws,
           unsigned* __restrict__ flags)
{
    __shared__ __bf16 Wlds[16][KTOT + 8];   // 49408 B (bf16-rounded weights)
    __shared__ float  gbuf[64][17];         // 4352 B
    __shared__ float  obuf[4][16][17];      // 4352 B   (total 58112 B)

    const int tid = threadIdx.x;
    const int blk = blockIdx.x;       // 0..255
    const int j0  = blk * 4;
    const int ob0 = (blk >> 5) * 8;   // out-proj batch group (8 batches)
    const int oc0 = (blk & 31) * 16;  // out-proj col group (16 cols)

    // Stage resident gate-weight slab (f32 -> bf16)
    for (int idx = tid; idx < 16 * KTOT; idx += 256) {
        int k = idx >> 4, c = idx & 15;
        int gc = (c >> 2) * H_ + j0 + (c & 3);
        float w = (k < IN_) ? Wi[(size_t)k * G4_ + gc]
                            : Wh[(size_t)(k - IN_) * G4_ + gc];
        Wlds[c][k] = (__bf16)w;
    }
    __syncthreads();

    const int lane = tid & 63;
    const int wave = tid >> 6;
    const int c    = lane & 15;
    const int quad = lane >> 4;
    const int rowA = wave * 16 + c;   // batch row for gate A-frags
    const int kq   = quad * 8;

    const float biasv = bias[(c >> 2) * H_ + j0 + (c & 3)];

    // Hoist step-invariant Wo fragments into registers (f32 -> bf16)
    bf8v wof[8];
    #pragma unroll
    for (int kk = 0; kk < 8; ++kk) {
        int kbase = wave * 256 + kk * 32 + kq;
        #pragma unroll
        for (int j = 0; j < 8; ++j)
            wof[kk][j] = (__bf16)Wo[(size_t)(kbase + j) * OUT_ + oc0 + c];
    }

    // recurrent cell state: thread owns (batch = tid>>2, j = j0 + (tid&3))
    float c_reg = 0.f;
    const int bb = tid >> 2;
    const int jo = tid & 3;

    // x partial accumulators for the upcoming step (prologue: t=0)
    f4v xacc0 = {0.f, 0.f, 0.f, 0.f};
    f4v xacc1 = {0.f, 0.f, 0.f, 0.f};
    X_PRE(0, xacc0, xacc1);

    const size_t bufsz = (size_t)2 * B_ * H_;   // bf16 per buffer (hi+lo planes)

    for (int t = 0; t < T_; ++t) {
        asm volatile("" ::: "memory");   // pin loads below the barrier exit
        const int br = (t + 2) % 3;   // buffer holding h_{t-1}
        const int bw = t % 3;         // buffer for h_t
        const __bf16* hhi_p = hws + (size_t)br * bufsz;
        const __bf16* hlo_p = hhi_p + B_ * H_;
        __bf16* hhi_c = hws + (size_t)bw * bufsz;
        __bf16* hlo_c = hhi_c + B_ * H_;

        // ---- phase A: gate MFMA for step t (x part precomputed) ----
        f4v acc0 = xacc0;   // hi-product chain
        f4v acc1 = xacc1;   // lo-product chain
        if (t > 0) {
            const __bf16* hh = hhi_p + (size_t)rowA * H_ + kq;
            const __bf16* hl = hlo_p + (size_t)rowA * H_ + kq;
            f4v Ah0[8], Al0[8], Ah1[8], Al1[8];   // 128 declared (proven cap)
            GISSUE(Ah0, Al0, 0);      // G0   [16]
            GISSUE(Ah1, Al1, 8);      // G1   [32]
            VM_WAIT(16);              // G0 retired
            GCONSUME(Ah0, Al0, 0);
            GISSUE(Ah0, Al0, 16);     // G2 into G0's registers
            VM_WAIT(16);              // G1 retired
            GCONSUME(Ah1, Al1, 8);
            GISSUE(Ah1, Al1, 24);     // G3 into G1's registers
            VM_WAIT(16);              // G2 retired
            GCONSUME(Ah0, Al0, 16);
            VM_WAIT(0);               // G3 retired
            GCONSUME(Ah1, Al1, 24);
        }
        f4v acc = acc0 + acc1;
        #pragma unroll
        for (int r = 0; r < 4; ++r)
            gbuf[wave * 16 + quad * 4 + r][c] = acc[r] + biasv;  // C: col=c, row=quad*4+r
        // NO __syncthreads: phase B reads only THIS wave's gbuf rows
        // (bb = tid>>2 in [16w, 16w+16) for tid in wave w).
        asm volatile("s_waitcnt lgkmcnt(0)");
        __builtin_amdgcn_sched_barrier(0);

        // ---- phase B: elementwise cell update, write h_t (hi+lo, write-through) ----
        {
            float gi = gbuf[bb][jo];
            float gf = gbuf[bb][4 + jo];
            float gg = gbuf[bb][8 + jo];
            float go = gbuf[bb][12 + jo];
            c_reg = sigm(gf) * c_reg + sigm(gi) * tanh_f(gg);
            float hn = sigm(go) * tanh_f(c_reg);
            __bf16 hh2 = (__bf16)hn;
            store_bf16_wt(&hhi_c[(size_t)bb * H_ + j0 + jo], hh2);
            store_bf16_wt(&hlo_c[(size_t)bb * H_ + j0 + jo], (__bf16)(hn - (float)hh2));
        }

        // ==== arrive; shadow work; poll (NO fence anywhere) ====
        __syncthreads();   // drains vmcnt: all waves' sc0sc1 h stores ack'd at LLC
        const unsigned tgt = (unsigned)(t + 1);
        if (tid == 0) {
            unsigned* p = &flags[blk * 16];
            asm volatile("global_store_dword %0, %1, off sc0 sc1"
                         :: "v"(p), "v"(tgt) : "memory");
        }

        // ---- shadow 1: out-proj partial for step t-1 (LLC-direct reads).
        // Race-free: buf br next overwritten at step t+2's phase B, which
        // is ordered after barrier(t+1), which needs our flag(t+1), set
        // before this point.
        if (t > 0) {
            f4v Oh[8], Ol[8];
            #pragma unroll
            for (int kk = 0; kk < 8; ++kk) {
                Oh[kk] = (f4v){0.f, 0.f, 0.f, 0.f};
                Ol[kk] = (f4v){0.f, 0.f, 0.f, 0.f};
            }
            const __bf16* orh = hhi_p + (size_t)(ob0 + c) * H_;
            const __bf16* orl = hlo_p + (size_t)(ob0 + c) * H_;
            if (c < 8) {   // A rows 8..15 zero (8 batches per tile)
                #pragma unroll
                for (int kk = 0; kk < 8; ++kk) {
                    GLOAD(Oh[kk], orh + wave * 256 + kk * 32 + kq);
                    GLOAD(Ol[kk], orl + wave * 256 + kk * 32 + kq);
                }
            }
            VM_WAIT(0);
            f4v oac = {0.f, 0.f, 0.f, 0.f};
            #pragma unroll
            for (int kk = 0; kk < 8; ++kk) {
                oac = __builtin_amdgcn_mfma_f32_16x16x32_bf16(
                    __builtin_bit_cast(bf8v, Oh[kk]), wof[kk], oac, 0, 0, 0);
                oac = __builtin_amdgcn_mfma_f32_16x16x32_bf16(
                    __builtin_bit_cast(bf8v, Ol[kk]), wof[kk], oac, 0, 0, 0);
            }
            #pragma unroll
            for (int r = 0; r < 4; ++r)
                obuf[wave][quad * 4 + r][c] = oac[r];
        }
        __syncthreads();   // obuf visible to reducers (intra-block)

        // ---- shadow 2: reduce out-proj partials, store out[:, t-1, :] ----
        if (t > 0 && tid < 128) {
            int m = tid >> 4, cc = tid & 15;
            float v = obuf[0][m][cc] + obuf[1][m][cc] + obuf[2][m][cc] + obuf[3][m][cc]
                    + bo[oc0 + cc];
            out[(((size_t)(ob0 + m)) * T_ + (t - 1)) * OUT_ + oc0 + cc] = v;
        }

        // ---- shadow 3: x-part of step t+1 (no dependence on h_t) ----
        xacc0 = (f4v){0.f, 0.f, 0.f, 0.f};
        xacc1 = (f4v){0.f, 0.f, 0.f, 0.f};
        if (t + 1 < T_) {
            X_PRE(t + 1, xacc0, xacc1);
        }
        asm volatile("" ::: "memory");   // pin shadow loads above the poll

        // ---- wait (relaxed poll; no fence: h readers are LLC-direct) ----
        if (tid < 64) {
            const int lane2 = tid;
            for (;;) {
                unsigned m0 = __hip_atomic_load(&flags[(lane2 * 4 + 0) * 16],
                                                __ATOMIC_RELAXED, __HIP_MEMORY_SCOPE_AGENT);
                unsigned m1 = __hip_atomic_load(&flags[(lane2 * 4 + 1) * 16],
                                                __ATOMIC_RELAXED, __HIP_MEMORY_SCOPE_AGENT);
                unsigned m2 = __hip_atomic_load(&flags[(lane2 * 4 + 2) * 16],
                                                __ATOMIC_RELAXED, __HIP_MEMORY_SCOPE_AGENT);
                unsigned m3 = __hip_atomic_load(&flags[(lane2 * 4 + 3) * 16],
                                                __ATOMIC_RELAXED, __HIP_MEMORY_SCOPE_AGENT);
                bool ok = (m0 >= tgt) & (m1 >= tgt) & (m2 >= tgt) & (m3 >= tgt);
                if (__all(ok)) break;
                __builtin_amdgcn_s_sleep(1);
            }
        }
        __syncthreads();
    }

    // ---- epilogue: out-proj for t = T-1 (h_{T-1} in buf (T-1)%3 = 0) ----
    {
        const __bf16* hhi_l = hws;            // buf 0
        const __bf16* hlo_l = hws + B_ * H_;
        f4v Oh[8], Ol[8];
        #pragma unroll
        for (int kk = 0; kk < 8; ++kk) {
            Oh[kk] = (f4v){0.f, 0.f, 0.f, 0.f};
            Ol[kk] = (f4v){0.f, 0.f, 0.f, 0.f};
        }
        const __bf16* orh = hhi_l + (size_t)(ob0 + c) * H_;
        const __bf16* orl = hlo_l + (size_t)(ob0 + c) * H_;
        if (c < 8) {
            #pragma unroll
            for (int kk = 0; kk < 8; ++kk) {
                GLOAD(Oh[kk], orh + wave * 256 + kk * 32 + kq);
                GLOAD(Ol[kk], orl + wave * 256 + kk * 32 + kq);
            }
        }
        VM_WAIT(0);
        f4v oac = {0.f, 0.f, 0.f, 0.f};
        #pragma unroll
        for (int kk = 0; kk < 8; ++kk) {
            oac = __builtin_amdgcn_mfma_f32_16x16x32_bf16(
                __builtin_bit_cast(bf8v, Oh[kk]), wof[kk], oac, 0, 0, 0);
            oac = __builtin_amdgcn_mfma_f32_16x16x32_bf16(
                __builtin_bit_cast(bf8v, Ol[kk]), wof[kk], oac, 0, 0, 0);
        }
        #pragma unroll
        for (int r = 0; r < 4; ++r)
            obuf[wave][quad * 4 + r][c] = oac[r];
        __syncthreads();
        if (tid < 128) {
            int m = tid >> 4, cc = tid & 15;
            float v = obuf[0][m][cc] + obuf[1][m][cc] + obuf[2][m][cc] + obuf[3][m][cc]
                    + bo[oc0 + cc];
            out[(((size_t)(ob0 + m)) * T_ + (T_ - 1)) * OUT_ + oc0 + cc] = v;
        }
    }
}

extern "C" void kernel_launch(void* const* d_in, const int* in_sizes, int n_in,
                              void* d_out, int out_size, void* d_ws, size_t ws_size,
                              hipStream_t stream) {
    const float* xs = (const float*)d_in[0];
    const float* Wi = (const float*)d_in[1];
    const float* Wh = (const float*)d_in[2];
    const float* b  = (const float*)d_in[3];
    const float* Wo = (const float*)d_in[4];
    const float* bo = (const float*)d_in[5];
    float* out = (float*)d_out;

    // ws layout: [0,16K) flag vector (256 x 64B-padded, zeroed);
    //            [64K, +768K) h TRIPLE buffer (hi/lo planes, bf16)
    unsigned* flags = (unsigned*)d_ws;         // flags[i*16], i = 0..255
    __bf16*   hws   = (__bf16*)((char*)d_ws + 65536);

    hipMemsetAsync(d_ws, 0, 32768, stream);    // reset flags (graph-capture safe)

    void* args[] = {(void*)&xs, (void*)&Wi, (void*)&Wh, (void*)&b,
                    (void*)&Wo, (void*)&bo, (void*)&out, (void*)&hws,
                    (void*)&flags};
    hipLaunchCooperativeKernel((void*)lstm_fused, dim3(256), dim3(256), args, 0, stream);
}

// Round 19
// 3544.712 us; speedup vs baseline: 1.1325x; 1.0548x over previous
//
#include <hip/hip_runtime.h>
#include <hip/hip_cooperative_groups.h>

// LSTM: B=64, T=256, IN=512, H=1024 (4H=4096), OUT=512. I/O f32.
// Round-29 = r28 (A2-loads folded into the gate burst) + ONE fix:
// explicit VM_WAIT(0) after phase B, BEFORE the arrive-__syncthreads.
//   r28 post-mortem (absmax NaN = ran-but-garbage, only `out`
//   NaN-able): __syncthreads does NOT drain inline-asm vmem ops (no
//   "memory" clobber on GLOAD -> compiler's barrier lowering emits no
//   vmcnt(0) for them). Shadow-1 consumed O registers before retire.
//   r25's version of the fold passed because it ended phase A with
//   VM_WAIT(0). Fix keeps the fold's overlap (O retires under
//   G3-consume + gbuf + phase B ~1.5us >> 0.9us RTT) and also makes
//   the h-store -> flag ordering architecturally sound (the stores
//   are drained by the same wait, no longer by luck).
//   Envelope rules: <=128 declared asm staging VGPRs, <=64KB static
//   LDS, no attr calls.
// Coherence: h stores sc0sc1 -> VM_WAIT(0) -> arrive sync -> flag
// store sc0sc1 -> relaxed poll -> LLC-direct reads. NO fences.
// A2 math order unchanged -> absmax must stay exactly 0.0078125.
// ws: [0,16K) flags; [64K, +768K) h triple buffer (hi/lo planes).

#define B_   64
#define T_   256
#define IN_  512
#define H_   1024
#define G4_  4096
#define OUT_ 512
#define KTOT 1536   // IN_ + H_

typedef __bf16 bf8v  __attribute__((ext_vector_type(8)));
typedef float  f4v   __attribute__((ext_vector_type(4)));

__device__ __forceinline__ float sigm(float x) { return 1.f / (1.f + __expf(-x)); }
__device__ __forceinline__ float tanh_f(float x) { return 1.f - 2.f / (__expf(2.f * x) + 1.f); }

// LLC-direct 16B load (bypass L1+L2). Tracked manually via vmcnt.
#define GLOAD(dst, p) \
    asm volatile("global_load_dwordx4 %0, %1, off sc0 sc1" \
                 : "=v"(dst) : "v"(p))

#define VM_WAIT(n) do { \
    asm volatile("s_waitcnt vmcnt(" #n ")"); \
    __builtin_amdgcn_sched_barrier(0); \
} while (0)

// Write-through store of one bf16, bypassing L1 (sc0) and L2 (sc1).
__device__ __forceinline__ void store_bf16_wt(__bf16* p, __bf16 v) {
    union { __bf16 b; unsigned short s; } cv; cv.b = v;
    unsigned w = cv.s;
    asm volatile("global_store_short %0, %1, off sc0 sc1"
                 :: "v"(p), "v"(w) : "memory");
}

// x-part of the gate GEMM for timestep tt (r12 order). Plain cached
// loads: x is read-only and, with no invalidates, stays L2-resident.
#define X_PRE(tt, xa0, xa1)                                                   \
    {                                                                         \
        const float* xrow = xs + ((size_t)rowA * T_ + (size_t)(tt)) * IN_ + kq; \
        _Pragma("unroll")                                                     \
        for (int ks = 0; ks < 16; ++ks) {                                     \
            f4v v0 = *(const f4v*)(xrow + ks * 32);                           \
            f4v v1 = *(const f4v*)(xrow + ks * 32 + 4);                       \
            bf8v ah, al;                                                      \
            _Pragma("unroll")                                                 \
            for (int j = 0; j < 4; ++j) {                                     \
                __bf16 h0 = (__bf16)v0[j], h1 = (__bf16)v1[j];                \
                ah[j] = h0;  ah[4 + j] = h1;                                  \
                al[j]     = (__bf16)(v0[j] - (float)h0);                      \
                al[4 + j] = (__bf16)(v1[j] - (float)h1);                      \
            }                                                                 \
            bf8v w = *(const bf8v*)&Wlds[c][ks * 32 + kq];                    \
            xa0 = __builtin_amdgcn_mfma_f32_16x16x32_bf16(ah, w, xa0, 0, 0, 0); \
            xa1 = __builtin_amdgcn_mfma_f32_16x16x32_bf16(al, w, xa1, 0, 0, 0); \
        }                                                                     \
    }

// issue one 8-iter group of gate h loads (16 LLC-direct loads)
#define GISSUE(Hreg, Lreg, kb)                                                \
    _Pragma("unroll")                                                         \
    for (int i = 0; i < 8; ++i) {                                             \
        GLOAD(Hreg[i], hh + ((kb) + i) * 32);                                 \
        GLOAD(Lreg[i], hl + ((kb) + i) * 32);                                 \
    }

// consume one 8-iter group (order identical to r12's ks sweep)
#define GCONSUME(Hreg, Lreg, kb)                                              \
    _Pragma("unroll")                                                         \
    for (int i = 0; i < 8; ++i) {                                             \
        bf8v w = *(const bf8v*)&Wlds[c][IN_ + ((kb) + i) * 32 + kq];          \
        acc0 = __builtin_amdgcn_mfma_f32_16x16x32_bf16(                       \
            __builtin_bit_cast(bf8v, Hreg[i]), w, acc0, 0, 0, 0);             \
        acc1 = __builtin_amdgcn_mfma_f32_16x16x32_bf16(                       \
            __builtin_bit_cast(bf8v, Lreg[i]), w, acc1, 0, 0, 0);             \
    }

__global__ void __launch_bounds__(256, 1)
lstm_fused(const float* __restrict__ xs, const float* __restrict__ Wi,
           const float* __restrict__ Wh, const float* __restrict__ bias,
           const float* __restrict__ Wo, const float* __restrict__ bo,
           float* __restrict__ out, __bf16* __restrict__ hws,
           unsigned* __restrict__ flags)
{
    __shared__ __bf16 Wlds[16][KTOT + 8];   // 49408 B (bf16-rounded weights)
    __shared__ float  gbuf[64][17];         // 4352 B
    __shared__ float  obuf[4][16][17];      // 4352 B   (total 58112 B)

    const int tid = threadIdx.x;
    const int blk = blockIdx.x;       // 0..255
    const int j0  = blk * 4;
    const int ob0 = (blk >> 5) * 8;   // out-proj batch group (8 batches)
    const int oc0 = (blk & 31) * 16;  // out-proj col group (16 cols)

    // Stage resident gate-weight slab (f32 -> bf16)
    for (int idx = tid; idx < 16 * KTOT; idx += 256) {
        int k = idx >> 4, c = idx & 15;
        int gc = (c >> 2) * H_ + j0 + (c & 3);
        float w = (k < IN_) ? Wi[(size_t)k * G4_ + gc]
                            : Wh[(size_t)(k - IN_) * G4_ + gc];
        Wlds[c][k] = (__bf16)w;
    }
    __syncthreads();

    const int lane = tid & 63;
    const int wave = tid >> 6;
    const int c    = lane & 15;
    const int quad = lane >> 4;
    const int rowA = wave * 16 + c;   // batch row for gate A-frags
    const int kq   = quad * 8;

    const float biasv = bias[(c >> 2) * H_ + j0 + (c & 3)];

    // Hoist step-invariant Wo fragments into registers (f32 -> bf16)
    bf8v wof[8];
    #pragma unroll
    for (int kk = 0; kk < 8; ++kk) {
        int kbase = wave * 256 + kk * 32 + kq;
        #pragma unroll
        for (int j = 0; j < 8; ++j)
            wof[kk][j] = (__bf16)Wo[(size_t)(kbase + j) * OUT_ + oc0 + c];
    }

    // recurrent cell state: thread owns (batch = tid>>2, j = j0 + (tid&3))
    float c_reg = 0.f;
    const int bb = tid >> 2;
    const int jo = tid & 3;

    // x partial accumulators for the upcoming step (prologue: t=0)
    f4v xacc0 = {0.f, 0.f, 0.f, 0.f};
    f4v xacc1 = {0.f, 0.f, 0.f, 0.f};
    X_PRE(0, xacc0, xacc1);

    const size_t bufsz = (size_t)2 * B_ * H_;   // bf16 per buffer (hi+lo planes)

    for (int t = 0; t < T_; ++t) {
        asm volatile("" ::: "memory");   // pin loads below the barrier exit
        const int br = (t + 2) % 3;   // buffer holding h_{t-1}
        const int bw = t % 3;         // buffer for h_t
        const __bf16* hhi_p = hws + (size_t)br * bufsz;
        const __bf16* hlo_p = hhi_p + B_ * H_;
        __bf16* hhi_c = hws + (size_t)bw * bufsz;
        __bf16* hlo_c = hhi_c + B_ * H_;

        // staging (exactly 128 declared VGPRs; Ah0/Al0 double as the
        // A2 fragment carrier from phase A into shadow-1)
        f4v Ah0[8], Al0[8], Ah1[8], Al1[8];

        // ---- phase A: gate MFMA for step t (x part precomputed);
        //      A2's loads fold into the tail of the burst ----
        f4v acc0 = xacc0;   // hi-product chain
        f4v acc1 = xacc1;   // lo-product chain
        if (t > 0) {
            const __bf16* hh = hhi_p + (size_t)rowA * H_ + kq;
            const __bf16* hl = hlo_p + (size_t)rowA * H_ + kq;
            const __bf16* orh = hhi_p + (size_t)(ob0 + c) * H_;
            const __bf16* orl = hlo_p + (size_t)(ob0 + c) * H_;
            GISSUE(Ah0, Al0, 0);      // G0   [16]
            GISSUE(Ah1, Al1, 8);      // G1   [32]
            VM_WAIT(16);              // G0 retired
            GCONSUME(Ah0, Al0, 0);
            GISSUE(Ah0, Al0, 16);     // G2 into G0's registers [32]
            VM_WAIT(16);              // G1 retired
            GCONSUME(Ah1, Al1, 8);
            GISSUE(Ah1, Al1, 24);     // G3 into G1's registers [32]
            VM_WAIT(16);              // G2 retired
            GCONSUME(Ah0, Al0, 16);
            // ---- fold: A2 loads into freed Ah0/Al0 [G3=16 + O=16] ----
            #pragma unroll
            for (int kk = 0; kk < 8; ++kk) {
                Ah0[kk] = (f4v){0.f, 0.f, 0.f, 0.f};
                Al0[kk] = (f4v){0.f, 0.f, 0.f, 0.f};
            }
            if (c < 8) {   // A rows 8..15 zero (8 batches per tile)
                #pragma unroll
                for (int kk = 0; kk < 8; ++kk) {
                    GLOAD(Ah0[kk], orh + wave * 256 + kk * 32 + kq);
                    GLOAD(Al0[kk], orl + wave * 256 + kk * 32 + kq);
                }
            }
            VM_WAIT(16);              // G3 retired (O stays in flight)
            GCONSUME(Ah1, Al1, 24);
        }
        f4v acc = acc0 + acc1;
        #pragma unroll
        for (int r = 0; r < 4; ++r)
            gbuf[wave * 16 + quad * 4 + r][c] = acc[r] + biasv;  // C: col=c, row=quad*4+r
        // NO __syncthreads: phase B reads only THIS wave's gbuf rows
        // (bb = tid>>2 in [16w, 16w+16) for tid in wave w).
        asm volatile("s_waitcnt lgkmcnt(0)");
        __builtin_amdgcn_sched_barrier(0);

        // ---- phase B: elementwise cell update, write h_t (hi+lo, write-through) ----
        {
            float gi = gbuf[bb][jo];
            float gf = gbuf[bb][4 + jo];
            float gg = gbuf[bb][8 + jo];
            float go = gbuf[bb][12 + jo];
            c_reg = sigm(gf) * c_reg + sigm(gi) * tanh_f(gg);
            float hn = sigm(go) * tanh_f(c_reg);
            __bf16 hh2 = (__bf16)hn;
            store_bf16_wt(&hhi_c[(size_t)bb * H_ + j0 + jo], hh2);
            store_bf16_wt(&hlo_c[(size_t)bb * H_ + j0 + jo], (__bf16)(hn - (float)hh2));
        }

        // ---- THE r29 FIX: drain O loads AND h stores before the arrive.
        // (inline-asm vmem ops are invisible to __syncthreads' barrier
        // lowering -> r28's NaN. O retired mostly under phase B already,
        // so this wait is near-free; it also makes h-store -> flag
        // ordering architecturally sound.)
        VM_WAIT(0);

        // ==== arrive; shadow work; poll (NO fence anywhere) ====
        __syncthreads();
        const unsigned tgt = (unsigned)(t + 1);
        if (tid == 0) {
            unsigned* p = &flags[blk * 16];
            asm volatile("global_store_dword %0, %1, off sc0 sc1"
                         :: "v"(p), "v"(tgt) : "memory");
        }

        // ---- shadow 1: out-proj MFMAs for step t-1 — fragments already in
        // Ah0/Al0 (loaded in phase A, drained by VM_WAIT(0)): NO loads,
        // NO wait. Race-free: buf br next overwritten at step t+2's phase B,
        // ordered after barrier(t+1), which needs our flag(t+1), set above.
        if (t > 0) {
            f4v oac = {0.f, 0.f, 0.f, 0.f};
            #pragma unroll
            for (int kk = 0; kk < 8; ++kk) {
                oac = __builtin_amdgcn_mfma_f32_16x16x32_bf16(
                    __builtin_bit_cast(bf8v, Ah0[kk]), wof[kk], oac, 0, 0, 0);
                oac = __builtin_amdgcn_mfma_f32_16x16x32_bf16(
                    __builtin_bit_cast(bf8v, Al0[kk]), wof[kk], oac, 0, 0, 0);
            }
            #pragma unroll
            for (int r = 0; r < 4; ++r)
                obuf[wave][quad * 4 + r][c] = oac[r];
        }
        __syncthreads();   // obuf visible to reducers (intra-block)

        // ---- shadow 2: reduce out-proj partials, store out[:, t-1, :] ----
        if (t > 0 && tid < 128) {
            int m = tid >> 4, cc = tid & 15;
            float v = obuf[0][m][cc] + obuf[1][m][cc] + obuf[2][m][cc] + obuf[3][m][cc]
                    + bo[oc0 + cc];
            out[(((size_t)(ob0 + m)) * T_ + (t - 1)) * OUT_ + oc0 + cc] = v;
        }

        // ---- shadow 3: x-part of step t+1 (no dependence on h_t) ----
        xacc0 = (f4v){0.f, 0.f, 0.f, 0.f};
        xacc1 = (f4v){0.f, 0.f, 0.f, 0.f};
        if (t + 1 < T_) {
            X_PRE(t + 1, xacc0, xacc1);
        }
        asm volatile("" ::: "memory");   // pin shadow loads above the poll

        // ---- wait (relaxed poll; no fence: h readers are LLC-direct) ----
        if (tid < 64) {
            const int lane2 = tid;
            for (;;) {
                unsigned m0 = __hip_atomic_load(&flags[(lane2 * 4 + 0) * 16],
                                                __ATOMIC_RELAXED, __HIP_MEMORY_SCOPE_AGENT);
                unsigned m1 = __hip_atomic_load(&flags[(lane2 * 4 + 1) * 16],
                                                __ATOMIC_RELAXED, __HIP_MEMORY_SCOPE_AGENT);
                unsigned m2 = __hip_atomic_load(&flags[(lane2 * 4 + 2) * 16],
                                                __ATOMIC_RELAXED, __HIP_MEMORY_SCOPE_AGENT);
                unsigned m3 = __hip_atomic_load(&flags[(lane2 * 4 + 3) * 16],
                                                __ATOMIC_RELAXED, __HIP_MEMORY_SCOPE_AGENT);
                bool ok = (m0 >= tgt) & (m1 >= tgt) & (m2 >= tgt) & (m3 >= tgt);
                if (__all(ok)) break;
                __builtin_amdgcn_s_sleep(1);
            }
        }
        __syncthreads();
    }

    // ---- epilogue: out-proj for t = T-1 (h_{T-1} in buf (T-1)%3 = 0) ----
    {
        const __bf16* hhi_l = hws;            // buf 0
        const __bf16* hlo_l = hws + B_ * H_;
        f4v Oh[8], Ol[8];
        #pragma unroll
        for (int kk = 0; kk < 8; ++kk) {
            Oh[kk] = (f4v){0.f, 0.f, 0.f, 0.f};
            Ol[kk] = (f4v){0.f, 0.f, 0.f, 0.f};
        }
        const __bf16* orh = hhi_l + (size_t)(ob0 + c) * H_;
        const __bf16* orl = hlo_l + (size_t)(ob0 + c) * H_;
        if (c < 8) {
            #pragma unroll
            for (int kk = 0; kk < 8; ++kk) {
                GLOAD(Oh[kk], orh + wave * 256 + kk * 32 + kq);
                GLOAD(Ol[kk], orl + wave * 256 + kk * 32 + kq);
            }
        }
        VM_WAIT(0);
        f4v oac = {0.f, 0.f, 0.f, 0.f};
        #pragma unroll
        for (int kk = 0; kk < 8; ++kk) {
            oac = __builtin_amdgcn_mfma_f32_16x16x32_bf16(
                __builtin_bit_cast(bf8v, Oh[kk]), wof[kk], oac, 0, 0, 0);
            oac = __builtin_amdgcn_mfma_f32_16x16x32_bf16(
                __builtin_bit_cast(bf8v, Ol[kk]), wof[kk], oac, 0, 0, 0);
        }
        #pragma unroll
        for (int r = 0; r < 4; ++r)
            obuf[wave][quad * 4 + r][c] = oac[r];
        __syncthreads();
        if (tid < 128) {
            int m = tid >> 4, cc = tid & 15;
            float v = obuf[0][m][cc] + obuf[1][m][cc] + obuf[2][m][cc] + obuf[3][m][cc]
                    + bo[oc0 + cc];
            out[(((size_t)(ob0 + m)) * T_ + (T_ - 1)) * OUT_ + oc0 + cc] = v;
        }
    }
}

extern "C" void kernel_launch(void* const* d_in, const int* in_sizes, int n_in,
                              void* d_out, int out_size, void* d_ws, size_t ws_size,
                              hipStream_t stream) {
    const float* xs = (const float*)d_in[0];
    const float* Wi = (const float*)d_in[1];
    const float* Wh = (const float*)d_in[2];
    const float* b  = (const float*)d_in[3];
    const float* Wo = (const float*)d_in[4];
    const float* bo = (const float*)d_in[5];
    float* out = (float*)d_out;

    // ws layout: [0,16K) flag vector (256 x 64B-padded, zeroed);
    //            [64K, +768K) h TRIPLE buffer (hi/lo planes, bf16)
    unsigned* flags = (unsigned*)d_ws;         // flags[i*16], i = 0..255
    __bf16*   hws   = (__bf16*)((char*)d_ws + 65536);

    hipMemsetAsync(d_ws, 0, 32768, stream);    // reset flags (graph-capture safe)

    void* args[] = {(void*)&xs, (void*)&Wi, (void*)&Wh, (void*)&b,
                    (void*)&Wo, (void*)&bo, (void*)&out, (void*)&hws,
                    (void*)&flags};
    hipLaunchCooperativeKernel((void*)lstm_fused, dim3(256), dim3(256), args, 0, stream);
}